// Round 1
// baseline (7973.862 us; speedup 1.0000x reference)
//
#include <hip/hip_runtime.h>

#define T_STEPS 4096
#define M_BATCH 512
#define D_INP   11
#define N_HID   51

typedef float v4f __attribute__((ext_vector_type(4)));

__device__ __forceinline__ float sigmoid_fast(float v) {
    return __builtin_amdgcn_rcpf(1.0f + __expf(-v));
}
__device__ __forceinline__ float tanh_fast(float v) {
    return 2.0f * __builtin_amdgcn_rcpf(1.0f + __expf(-2.0f * v)) - 1.0f;
}

// Wave-specialized 2-layer LSTM, one block (128 threads = 2 waves) per batch
// column.  wave0 lane n owns L1 unit n: computes ALL 4 gates (i,f,g,o) of
// unit n for step t, updates c1/h1 in-register, writes only h1[n] to LDS.
// wave1 lane n owns L2 unit n (lagged one step: step t-1) + fused projection.
// This cuts LDS broadcast reads from ~93 to ~45 b128/block/step (the measured
// bottleneck: 186 b128/CU * ~12cyc ~= the whole 2600-cycle step) and needs
// only ONE barrier per step (gate exchange via LDS eliminated entirely).
// Weights: 104 v4f/thread shared array -> needs 1 wave/SIMD (512-reg budget).
__attribute__((amdgpu_waves_per_eu(1, 1)))
__global__ __launch_bounds__(128)
void lstm2_wavespec(const float* __restrict__ input,
                    const float* __restrict__ W_ih1, const float* __restrict__ W_hh1,
                    const float* __restrict__ b_ih1, const float* __restrict__ b_hh1,
                    const float* __restrict__ W_ih2, const float* __restrict__ W_hh2,
                    const float* __restrict__ b_ih2, const float* __restrict__ b_hh2,
                    const float* __restrict__ W_lin, const float* __restrict__ b_lin,
                    float* __restrict__ out)
{
    const int  tid  = threadIdx.x;
    const int  col  = blockIdx.x;
    const int  wid  = tid >> 6;
    const int  lane = tid & 63;
    const bool valid = lane < N_HID;

    __shared__ __align__(16) float hbuf[2][52];     // h1 double buffer, [51]=0 pad
    __shared__ __align__(16) float h2buf[52];       // h2 single buffer (wave1-local RAW)
    __shared__ __align__(16) float xs[2][64 * 12];  // x chunks, stride 12, [11]=0 pad
    __shared__ float outbuf[128];

    // ---- persistent per-thread weights: one shared array for both waves ----
    // wave0: wv[i*4+q], i<3  : W_ih1 chunk i of gate q (cols 4i..4i+3, pad>=11)
    //        wv[i*4+q], 3<=i<16 : W_hh1 chunk i-3 of gate q (pad>=51)
    // wave1: wv[i*4+q], i<13 : W_ih2 chunk i;  13<=i<26 : W_hh2 chunk i-13
    v4f   wv[104];
    float bias[4];
    float wlin = 0.f;
    const float blin = b_lin[0];
    float cstate = 0.f;

    if (wid == 0) {
        #pragma unroll
        for (int q = 0; q < 4; ++q) {
            const int r = q * N_HID + lane;          // gate row, valid only if lane<51
            bias[q] = valid ? (b_ih1[r] + b_hh1[r]) : 0.f;
            #pragma unroll
            for (int i = 0; i < 3; ++i)
                #pragma unroll
                for (int e = 0; e < 4; ++e) {
                    const int k = 4 * i + e;
                    wv[i * 4 + q][e] = (valid && k < D_INP) ? W_ih1[r * D_INP + k] : 0.f;
                }
            #pragma unroll
            for (int i = 3; i < 16; ++i)
                #pragma unroll
                for (int e = 0; e < 4; ++e) {
                    const int k = 4 * (i - 3) + e;
                    wv[i * 4 + q][e] = (valid && k < N_HID) ? W_hh1[r * N_HID + k] : 0.f;
                }
        }
    } else {
        #pragma unroll
        for (int q = 0; q < 4; ++q) {
            const int r = q * N_HID + lane;
            bias[q] = valid ? (b_ih2[r] + b_hh2[r]) : 0.f;
            #pragma unroll
            for (int i = 0; i < 13; ++i)
                #pragma unroll
                for (int e = 0; e < 4; ++e) {
                    const int k = 4 * i + e;
                    wv[i * 4 + q][e] = (valid && k < N_HID) ? W_ih2[r * N_HID + k] : 0.f;
                }
            #pragma unroll
            for (int i = 13; i < 26; ++i)
                #pragma unroll
                for (int e = 0; e < 4; ++e) {
                    const int k = 4 * (i - 13) + e;
                    wv[i * 4 + q][e] = (valid && k < N_HID) ? W_hh2[r * N_HID + k] : 0.f;
                }
        }
        wlin = valid ? W_lin[lane] : 0.f;
    }

    auto xload = [&](int c, int e) -> float {        // e in [0,704)
        int s = e / 11, d = e - s * 11;
        int tc = c * 64 + s; if (tc > T_STEPS - 1) tc = T_STEPS - 1;
        return input[((size_t)tc * M_BATCH + col) * D_INP + d];
    };
    auto xput = [&](int buf, int e, float v) {
        int s = e / 11, d = e - s * 11;
        xs[buf][s * 12 + d] = v;
    };

    // ---- zero-init LDS, stage chunk 0 ----
    for (int i = tid; i < 2 * 52; i += 128) (&hbuf[0][0])[i] = 0.f;
    for (int i = tid; i < 52;     i += 128) h2buf[i] = 0.f;
    for (int i = tid; i < 2 * 64 * 12; i += 128) (&xs[0][0])[i] = 0.f;
    __syncthreads();
    #pragma unroll
    for (int i = 0; i < 6; ++i) {
        const int e = tid + 128 * i;
        if (e < 704) xput(0, e, xload(0, e));
    }
    __syncthreads();

    float xr[6];

    #pragma unroll 1
    for (int t = 0; t <= T_STEPS; ++t) {
        if ((t & 63) == 0) {                         // prefetch next x chunk early
            const int c = (t >> 6) + 1;
            #pragma unroll
            for (int i = 0; i < 6; ++i) {
                const int e = tid + 128 * i;
                xr[i] = (e < 704) ? xload(c, e) : 0.f;
            }
        }

        const v4f* h1p = (const v4f*)hbuf[(t + 1) & 1];   // h1(t-1)
        v4f acc0 = {0.f,0.f,0.f,0.f}, acc1 = acc0, acc2 = acc0, acc3 = acc0;

        if (wid == 0) {
            // ---- L1 step t: gates of unit `lane` over [x(t); h1(t-1)] ----
            const v4f* xp = (const v4f*)&xs[(t >> 6) & 1][(t & 63) * 12];
            #pragma unroll
            for (int i = 0; i < 3; ++i) {
                const v4f v = xp[i];
                acc0 += v * wv[i * 4 + 0]; acc1 += v * wv[i * 4 + 1];
                acc2 += v * wv[i * 4 + 2]; acc3 += v * wv[i * 4 + 3];
            }
            #pragma unroll
            for (int i = 3; i < 16; ++i) {
                const v4f h = h1p[i - 3];
                acc0 += h * wv[i * 4 + 0]; acc1 += h * wv[i * 4 + 1];
                acc2 += h * wv[i * 4 + 2]; acc3 += h * wv[i * 4 + 3];
            }
        } else {
            // ---- L2 step t-1: gates of unit `lane` over [h1(t-1); h2(t-2)] ----
            const v4f* h2p = (const v4f*)h2buf;
            #pragma unroll
            for (int i = 0; i < 13; ++i) {
                const v4f h = h1p[i];
                acc0 += h * wv[i * 4 + 0]; acc1 += h * wv[i * 4 + 1];
                acc2 += h * wv[i * 4 + 2]; acc3 += h * wv[i * 4 + 3];
            }
            #pragma unroll
            for (int i = 13; i < 26; ++i) {
                const v4f h = h2p[i - 13];
                acc0 += h * wv[i * 4 + 0]; acc1 += h * wv[i * 4 + 1];
                acc2 += h * wv[i * 4 + 2]; acc3 += h * wv[i * 4 + 3];
            }
        }

        // ---- shared epilogue: activations + in-register cell update ----
        const float pre0 = (acc0.x + acc0.y) + (acc0.z + acc0.w) + bias[0];
        const float pre1 = (acc1.x + acc1.y) + (acc1.z + acc1.w) + bias[1];
        const float pre2 = (acc2.x + acc2.y) + (acc2.z + acc2.w) + bias[2];
        const float pre3 = (acc3.x + acc3.y) + (acc3.z + acc3.w) + bias[3];
        const float iv = sigmoid_fast(pre0);
        const float fv = sigmoid_fast(pre1);
        const float gv = tanh_fast(pre2);
        const float ov = sigmoid_fast(pre3);
        if (!(wid == 1 && t == 0))                    // wave1 iter0 = step -1: skip
            cstate = fv * cstate + iv * gv;
        const float hv = ov * tanh_fast(cstate);

        if (wid == 0) {
            if (valid) hbuf[t & 1][lane] = hv;        // publish h1(t)
            if ((t & 63) == 1 && t >= 65) {           // coalesced 64-wide out flush
                const int tb = (t - 65) + lane;
                out[(size_t)col * T_STEPS + tb] = outbuf[tb & 127];
            }
        } else {
            if (valid && t >= 1) h2buf[lane] = hv;    // publish h2(t-1) (wave-local RAW ok)
            float part = (t >= 1) ? wlin * hv : 0.f;  // fused projection
            #pragma unroll
            for (int off = 32; off > 0; off >>= 1)
                part += __shfl_down(part, off, 64);
            if (lane == 0 && t >= 1) outbuf[(t - 1) & 127] = part + blin;
        }

        if ((t & 63) == 32) {                         // stash next x chunk
            const int buf = ((t >> 6) + 1) & 1;
            #pragma unroll
            for (int i = 0; i < 6; ++i) {
                const int e = tid + 128 * i;
                if (e < 704) xput(buf, e, xr[i]);
            }
        }
        __syncthreads();                              // ONE barrier per step
    }

    if (wid == 0) {                                   // final 64 outputs
        const int idx = 4032 + lane;
        out[(size_t)col * T_STEPS + idx] = outbuf[idx & 127];
    }
}

extern "C" void kernel_launch(void* const* d_in, const int* in_sizes, int n_in,
                              void* d_out, int out_size, void* d_ws, size_t ws_size,
                              hipStream_t stream) {
    const float* input = (const float*)d_in[0];
    const float* W_ih1 = (const float*)d_in[1];
    const float* W_hh1 = (const float*)d_in[2];
    const float* b_ih1 = (const float*)d_in[3];
    const float* b_hh1 = (const float*)d_in[4];
    const float* W_ih2 = (const float*)d_in[5];
    const float* W_hh2 = (const float*)d_in[6];
    const float* b_ih2 = (const float*)d_in[7];
    const float* b_hh2 = (const float*)d_in[8];
    const float* W_lin = (const float*)d_in[9];
    const float* b_lin = (const float*)d_in[10];
    float* out = (float*)d_out;

    lstm2_wavespec<<<M_BATCH, 128, 0, stream>>>(
        input, W_ih1, W_hh1, b_ih1, b_hh1,
        W_ih2, W_hh2, b_ih2, b_hh2, W_lin, b_lin, out);
}

// Round 2
// 6153.985 us; speedup vs baseline: 1.2957x; 1.2957x over previous
//
#include <hip/hip_runtime.h>

#define T_STEPS 4096
#define M_BATCH 512
#define D_INP   11
#define N_HID   51

typedef float v4f __attribute__((ext_vector_type(4)));

__device__ __forceinline__ float sigmoid_fast(float v) {
    return __builtin_amdgcn_rcpf(1.0f + __expf(-v));
}
__device__ __forceinline__ float tanh_fast(float v) {
    return 2.0f * __builtin_amdgcn_rcpf(1.0f + __expf(-2.0f * v)) - 1.0f;
}

// k-split wave-specialized 2-layer LSTM.  One block (4 waves) per batch col.
// Each lane owns one hidden unit and ALL 4 of its gates, but only a k-slice:
//   wave0: L1, k = x(11) + h1[0:20)   -> 32 v4f weights (128 regs)
//   wave1: L1, k = h1[20:51]          -> 32 v4f
//   wave2: L2 (lag 1 step), k = h1    -> 52 v4f (208 regs)
//   wave3: L2 (lag 1 step), k = h2    -> 52 v4f
// Partials combined via one v4f LDS write/read (w1->w0, w3->w2); w0 updates
// c1/h1 in-register, w2 updates c2/h2 + fused projection.  2 barriers/step.
// Per-block broadcast reads drop 116 -> ~46 ds_read_b128 per step (the
// measured round-0 bottleneck), while per-thread weights stay <= 208 regs
// so nothing spills (round-1 failure mode: 416-reg demand -> scratch).
__attribute__((amdgpu_waves_per_eu(2, 2)))
__global__ __launch_bounds__(256)
void lstm2_ksplit(const float* __restrict__ input,
                  const float* __restrict__ W_ih1, const float* __restrict__ W_hh1,
                  const float* __restrict__ b_ih1, const float* __restrict__ b_hh1,
                  const float* __restrict__ W_ih2, const float* __restrict__ W_hh2,
                  const float* __restrict__ b_ih2, const float* __restrict__ b_hh2,
                  const float* __restrict__ W_lin, const float* __restrict__ b_lin,
                  float* __restrict__ out)
{
    const int  tid   = threadIdx.x;
    const int  col   = blockIdx.x;
    const int  wid   = tid >> 6;
    const int  lane  = tid & 63;
    const bool valid = lane < N_HID;
    const int  ln    = valid ? lane : 0;          // clamped row index (no OOB)

    __shared__ __align__(16) float hbuf[2][52];   // h1 double buffer, [51]=0 pad
    __shared__ __align__(16) float h2buf[52];     // h2 single buffer
    __shared__ __align__(16) float xs[2][64 * 12];// x chunks, stride 12, [11]=0 pad
    __shared__ __align__(16) v4f   pbuf1[64];     // wave1 -> wave0 partials
    __shared__ __align__(16) v4f   pbuf2[64];     // wave3 -> wave2 partials
    __shared__ float outbuf[128];

    // ---- persistent per-thread weights: wv[c*4+q], c = wave-local k-chunk ----
    v4f wv[52];
    #pragma unroll
    for (int i = 0; i < 52; ++i) wv[i] = (v4f){0.f, 0.f, 0.f, 0.f};
    float bias[4] = {0.f, 0.f, 0.f, 0.f};
    float wlin = 0.f;
    const float blin = b_lin[0];
    float cstate = 0.f;

    if (wid == 0) {
        #pragma unroll
        for (int q = 0; q < 4; ++q) {
            const int r = q * N_HID + ln;
            if (valid) bias[q] = b_ih1[r] + b_hh1[r];
            #pragma unroll
            for (int c = 0; c < 3; ++c)                  // x chunks
                #pragma unroll
                for (int e = 0; e < 4; ++e) {
                    const int k = 4 * c + e;
                    wv[c * 4 + q][e] = (valid && k < D_INP) ? W_ih1[r * D_INP + k] : 0.f;
                }
            #pragma unroll
            for (int c = 3; c < 8; ++c)                  // h1 k in [0,20)
                #pragma unroll
                for (int e = 0; e < 4; ++e) {
                    const int k = 4 * (c - 3) + e;
                    wv[c * 4 + q][e] = valid ? W_hh1[r * N_HID + k] : 0.f;
                }
        }
    } else if (wid == 1) {
        #pragma unroll
        for (int q = 0; q < 4; ++q) {
            const int r = q * N_HID + ln;
            #pragma unroll
            for (int c = 0; c < 8; ++c)                  // h1 k in [20,52), 51=pad
                #pragma unroll
                for (int e = 0; e < 4; ++e) {
                    const int k = 20 + 4 * c + e;
                    wv[c * 4 + q][e] = (valid && k < N_HID) ? W_hh1[r * N_HID + k] : 0.f;
                }
        }
    } else if (wid == 2) {
        #pragma unroll
        for (int q = 0; q < 4; ++q) {
            const int r = q * N_HID + ln;
            if (valid) bias[q] = b_ih2[r] + b_hh2[r];
            #pragma unroll
            for (int c = 0; c < 13; ++c)                 // h1 full
                #pragma unroll
                for (int e = 0; e < 4; ++e) {
                    const int k = 4 * c + e;
                    wv[c * 4 + q][e] = (valid && k < N_HID) ? W_ih2[r * N_HID + k] : 0.f;
                }
        }
        wlin = valid ? W_lin[ln] : 0.f;
    } else {
        #pragma unroll
        for (int q = 0; q < 4; ++q) {
            const int r = q * N_HID + ln;
            #pragma unroll
            for (int c = 0; c < 13; ++c)                 // h2 full
                #pragma unroll
                for (int e = 0; e < 4; ++e) {
                    const int k = 4 * c + e;
                    wv[c * 4 + q][e] = (valid && k < N_HID) ? W_hh2[r * N_HID + k] : 0.f;
                }
        }
    }

    auto xload = [&](int c, int e) -> float {            // e in [0,704)
        int s = e / 11, d = e - s * 11;
        int tc = c * 64 + s; if (tc > T_STEPS - 1) tc = T_STEPS - 1;
        return input[((size_t)tc * M_BATCH + col) * D_INP + d];
    };
    auto xput = [&](int buf, int e, float v) {
        int s = e / 11, d = e - s * 11;
        xs[buf][s * 12 + d] = v;
    };

    // ---- zero-init LDS, stage chunk 0 ----
    for (int i = tid; i < 2 * 52; i += 256) (&hbuf[0][0])[i] = 0.f;
    for (int i = tid; i < 52;     i += 256) h2buf[i] = 0.f;
    for (int i = tid; i < 2 * 64 * 12; i += 256) (&xs[0][0])[i] = 0.f;
    __syncthreads();
    {
        xput(0, tid, xload(0, tid));
        xput(0, tid + 256, xload(0, tid + 256));
        if (tid < 192) xput(0, tid + 512, xload(0, tid + 512));
    }
    __syncthreads();

    float xr0 = 0.f, xr1 = 0.f, xr2 = 0.f;

    #pragma unroll 1
    for (int t = 0; t <= T_STEPS; ++t) {
        if ((t & 63) == 0) {                             // prefetch next x chunk
            const int c = (t >> 6) + 1;
            xr0 = xload(c, tid);
            xr1 = xload(c, tid + 256);
            if (tid < 192) xr2 = xload(c, tid + 512);
        }

        const v4f* h1p = (const v4f*)hbuf[(t + 1) & 1];  // h1(t-1)
        v4f a0 = {0.f,0.f,0.f,0.f}, a1 = a0, a2 = a0, a3 = a0;

        if (wid == 0) {                                  // L1, x + h1[0:20)
            const v4f* xp = (const v4f*)&xs[(t >> 6) & 1][(t & 63) * 12];
            #pragma unroll
            for (int c = 0; c < 3; ++c) {
                const v4f v = xp[c];
                a0 += v * wv[c*4+0]; a1 += v * wv[c*4+1];
                a2 += v * wv[c*4+2]; a3 += v * wv[c*4+3];
            }
            #pragma unroll
            for (int c = 3; c < 8; ++c) {
                const v4f v = h1p[c - 3];
                a0 += v * wv[c*4+0]; a1 += v * wv[c*4+1];
                a2 += v * wv[c*4+2]; a3 += v * wv[c*4+3];
            }
        } else if (wid == 1) {                           // L1, h1[20:51]
            #pragma unroll
            for (int c = 0; c < 8; ++c) {
                const v4f v = h1p[c + 5];
                a0 += v * wv[c*4+0]; a1 += v * wv[c*4+1];
                a2 += v * wv[c*4+2]; a3 += v * wv[c*4+3];
            }
        } else if (wid == 2) {                           // L2 (t-1), h1 part
            #pragma unroll
            for (int c = 0; c < 13; ++c) {
                const v4f v = h1p[c];
                a0 += v * wv[c*4+0]; a1 += v * wv[c*4+1];
                a2 += v * wv[c*4+2]; a3 += v * wv[c*4+3];
            }
        } else {                                         // L2 (t-1), h2 part
            const v4f* h2p = (const v4f*)h2buf;
            #pragma unroll
            for (int c = 0; c < 13; ++c) {
                const v4f v = h2p[c];
                a0 += v * wv[c*4+0]; a1 += v * wv[c*4+1];
                a2 += v * wv[c*4+2]; a3 += v * wv[c*4+3];
            }
        }

        const float s0 = (a0.x + a0.y) + (a0.z + a0.w);
        const float s1 = (a1.x + a1.y) + (a1.z + a1.w);
        const float s2 = (a2.x + a2.y) + (a2.z + a2.w);
        const float s3 = (a3.x + a3.y) + (a3.z + a3.w);
        if (wid == 1)      pbuf1[lane] = (v4f){s0, s1, s2, s3};
        else if (wid == 3) pbuf2[lane] = (v4f){s0, s1, s2, s3};
        __syncthreads();                                 // B1: partials visible

        if (wid == 0) {                                  // c1/h1 update, step t
            const v4f p = pbuf1[lane];
            const float iv = sigmoid_fast(s0 + p.x + bias[0]);
            const float fv = sigmoid_fast(s1 + p.y + bias[1]);
            const float gv = tanh_fast   (s2 + p.z + bias[2]);
            const float ov = sigmoid_fast(s3 + p.w + bias[3]);
            cstate = fv * cstate + iv * gv;
            const float hv = ov * tanh_fast(cstate);
            if (valid) hbuf[t & 1][lane] = hv;           // publish h1(t)
        } else if (wid == 2) {                           // c2/h2 update, step t-1
            if (t >= 1) {
                const v4f p = pbuf2[lane];
                const float iv = sigmoid_fast(s0 + p.x + bias[0]);
                const float fv = sigmoid_fast(s1 + p.y + bias[1]);
                const float gv = tanh_fast   (s2 + p.z + bias[2]);
                const float ov = sigmoid_fast(s3 + p.w + bias[3]);
                cstate = fv * cstate + iv * gv;
                const float hv = ov * tanh_fast(cstate);
                if (valid) h2buf[lane] = hv;             // publish h2(t-1)
                float part = wlin * hv;                  // fused projection
                #pragma unroll
                for (int off = 32; off > 0; off >>= 1)
                    part += __shfl_down(part, off, 64);
                if (lane == 0) outbuf[(t - 1) & 127] = part + blin;
            }
        } else if (wid == 1) {                           // coalesced out flush
            if ((t & 63) == 1 && t >= 65) {
                const int tb = (t - 65) + lane;
                out[(size_t)col * T_STEPS + tb] = outbuf[tb & 127];
            }
        }

        if ((t & 63) == 32) {                            // stash next x chunk
            const int buf = ((t >> 6) + 1) & 1;
            xput(buf, tid, xr0);
            xput(buf, tid + 256, xr1);
            if (tid < 192) xput(buf, tid + 512, xr2);
        }
        __syncthreads();                                 // B2: h1/h2 visible
    }

    if (wid == 1) {                                      // final 64 outputs
        const int idx = 4032 + lane;
        out[(size_t)col * T_STEPS + idx] = outbuf[idx & 127];
    }
}

extern "C" void kernel_launch(void* const* d_in, const int* in_sizes, int n_in,
                              void* d_out, int out_size, void* d_ws, size_t ws_size,
                              hipStream_t stream) {
    const float* input = (const float*)d_in[0];
    const float* W_ih1 = (const float*)d_in[1];
    const float* W_hh1 = (const float*)d_in[2];
    const float* b_ih1 = (const float*)d_in[3];
    const float* b_hh1 = (const float*)d_in[4];
    const float* W_ih2 = (const float*)d_in[5];
    const float* W_hh2 = (const float*)d_in[6];
    const float* b_ih2 = (const float*)d_in[7];
    const float* b_hh2 = (const float*)d_in[8];
    const float* W_lin = (const float*)d_in[9];
    const float* b_lin = (const float*)d_in[10];
    float* out = (float*)d_out;

    lstm2_ksplit<<<M_BATCH, 256, 0, stream>>>(
        input, W_ih1, W_hh1, b_ih1, b_hh1,
        W_ih2, W_hh2, b_ih2, b_hh2, W_lin, b_lin, out);
}

// Round 3
// 5275.392 us; speedup vs baseline: 1.5115x; 1.1665x over previous
//
#include <hip/hip_runtime.h>

#define T_STEPS 4096
#define M_BATCH 512
#define D_INP   11
#define N_HID   51

typedef float v4f __attribute__((ext_vector_type(4)));

__device__ __forceinline__ float sigmoid_fast(float v) {
    return __builtin_amdgcn_rcpf(1.0f + __expf(-v));
}
__device__ __forceinline__ float tanh_fast(float v) {
    return 2.0f * __builtin_amdgcn_rcpf(1.0f + __expf(-2.0f * v)) - 1.0f;
}
// wave-uniform broadcast of lane l's value: v_readlane -> SGPR operand
__device__ __forceinline__ float RL(float v, int l) {
    return __uint_as_float(__builtin_amdgcn_readlane(__float_as_uint(v), l));
}

// SGPR-broadcast 2-layer LSTM.  One block (4 waves) per batch column.
// Acts are delivered via ONE distributed ds_read_b32 per wave (lane i holds
// slice elem i) + v_readlane -> SGPR, consumed as the scalar operand of
// v_fmac (legal: 1 SGPR src per VALU op).  This removes the per-lane
// replicated LDS broadcast (round-0 bottleneck: 232 b128/CU/step * ~12cyc).
// Every wave holds exactly 164 weight floats/thread (round-0-proven to fit
// the 256-reg unified budget at 2 waves/EU; rounds 1/2 failed by exceeding):
//   w0: L1 k={x(11),h1[0:20)} (31k) -> own   + L2 k=h1[0:10)  (10k) -> partial
//   w1: L1 k=h1[20:51)        (31k) -> part  + L2 k=h1[10:20) (10k) -> partial
//   w2: L2 k={h1[20:51),h2[0:10)} (41k) -> own (c2/h2 + fused projection)
//   w3: L2 k=h2[10:51)        (41k) -> partial
// L2 lags L1 by one step (classic 2-phase pipeline).  2 barriers/step.
__attribute__((amdgpu_waves_per_eu(2, 2)))
__global__ __launch_bounds__(256)
void lstm2_sgprbc(const float* __restrict__ input,
                  const float* __restrict__ W_ih1, const float* __restrict__ W_hh1,
                  const float* __restrict__ b_ih1, const float* __restrict__ b_hh1,
                  const float* __restrict__ W_ih2, const float* __restrict__ W_hh2,
                  const float* __restrict__ b_ih2, const float* __restrict__ b_hh2,
                  const float* __restrict__ W_lin, const float* __restrict__ b_lin,
                  float* __restrict__ out)
{
    const int  tid   = threadIdx.x;
    const int  col   = blockIdx.x;
    const int  wid   = tid >> 6;
    const int  lane  = tid & 63;
    const bool valid = lane < N_HID;
    const int  ln    = valid ? lane : 0;            // clamped unit index

    // hstate[p]: [0:51) = h1(t-1), [56:107) = h2(t-2) for iterations of parity p
    __shared__ __align__(16) float hstate[2][112];
    __shared__ __align__(16) float xs[2][64 * 12];  // x chunks, stride 12
    __shared__ __align__(16) v4f   pl1[64];         // w1 -> w0   L1 partial
    __shared__ __align__(16) v4f   pl2[3][64];      // w0,w1,w3 -> w2 L2 partials
    __shared__ float outbuf[128];

    // ---- per-thread weights: wA[31] (group A), wB[10] (group B), [k][gate] ----
    v4f wA[31], wB[10];
    v4f biasv = {0.f, 0.f, 0.f, 0.f};
    float wlin = 0.f;
    const float blin = b_lin[0];
    float cstate = 0.f;

    if (wid == 0) {
        #pragma unroll
        for (int q = 0; q < 4; ++q) {
            const int r = q * N_HID + ln;
            biasv[q] = valid ? (b_ih1[r] + b_hh1[r]) : 0.f;
            #pragma unroll
            for (int i = 0; i < 11; ++i) wA[i][q] = W_ih1[r * D_INP + i];       // x
            #pragma unroll
            for (int i = 11; i < 31; ++i) wA[i][q] = W_hh1[r * N_HID + (i - 11)]; // h1[0:20)
            #pragma unroll
            for (int j = 0; j < 10; ++j) wB[j][q] = W_ih2[r * N_HID + j];       // L2 h1[0:10)
        }
    } else if (wid == 1) {
        #pragma unroll
        for (int q = 0; q < 4; ++q) {
            const int r = q * N_HID + ln;
            #pragma unroll
            for (int i = 0; i < 31; ++i) wA[i][q] = W_hh1[r * N_HID + 20 + i];  // h1[20:51)
            #pragma unroll
            for (int j = 0; j < 10; ++j) wB[j][q] = W_ih2[r * N_HID + 10 + j];  // L2 h1[10:20)
        }
    } else if (wid == 2) {
        #pragma unroll
        for (int q = 0; q < 4; ++q) {
            const int r = q * N_HID + ln;
            biasv[q] = valid ? (b_ih2[r] + b_hh2[r]) : 0.f;
            #pragma unroll
            for (int i = 0; i < 31; ++i) wA[i][q] = W_ih2[r * N_HID + 20 + i];  // L2 h1[20:51)
            #pragma unroll
            for (int j = 0; j < 10; ++j) wB[j][q] = W_hh2[r * N_HID + j];       // L2 h2[0:10)
        }
        wlin = valid ? W_lin[ln] : 0.f;
    } else {
        #pragma unroll
        for (int q = 0; q < 4; ++q) {
            const int r = q * N_HID + ln;
            #pragma unroll
            for (int i = 0; i < 31; ++i) wA[i][q] = W_hh2[r * N_HID + 10 + i];  // h2[10:41)
            #pragma unroll
            for (int j = 0; j < 10; ++j) wB[j][q] = W_hh2[r * N_HID + 41 + j];  // h2[41:51)
        }
    }

    auto xload = [&](int c, int e) -> float {        // e in [0,704)
        int s = e / 11, d = e - s * 11;
        int tc = c * 64 + s; if (tc > T_STEPS - 1) tc = T_STEPS - 1;
        return input[((size_t)tc * M_BATCH + col) * D_INP + d];
    };
    auto xput = [&](int buf, int e, float v) {
        int s = e / 11, d = e - s * 11;
        xs[buf][s * 12 + d] = v;
    };

    // ---- zero-init LDS, stage x chunk 0 ----
    for (int i = tid; i < 2 * 112; i += 256) (&hstate[0][0])[i] = 0.f;
    for (int i = tid; i < 2 * 64 * 12; i += 256) (&xs[0][0])[i] = 0.f;
    for (int i = tid; i < 64; i += 256) { pl1[i] = (v4f){0,0,0,0};
        pl2[0][i] = (v4f){0,0,0,0}; pl2[1][i] = (v4f){0,0,0,0}; pl2[2][i] = (v4f){0,0,0,0}; }
    __syncthreads();
    {
        xput(0, tid, xload(0, tid));
        xput(0, tid + 256, xload(0, tid + 256));
        if (tid < 192) xput(0, tid + 512, xload(0, tid + 512));
    }
    __syncthreads();

    float xr0 = 0.f, xr1 = 0.f, xr2 = 0.f;

    #pragma unroll 1
    for (int t = 0; t <= T_STEPS; ++t) {
        if ((t & 63) == 0) {                          // prefetch next x chunk
            const int c = (t >> 6) + 1;
            xr0 = xload(c, tid);
            xr1 = xload(c, tid + 256);
            if (tid < 192) xr2 = xload(c, tid + 512);
        }

        const float* hs = &hstate[t & 1][0];
        v4f accA = {0.f,0.f,0.f,0.f}, accB = {0.f,0.f,0.f,0.f};
        float actv;

        if (wid == 0) {
            // slice: lanes 0-10 = x(t), lanes 11-30 = h1[0:20)
            const float* xp = &xs[(t >> 6) & 1][(t & 63) * 12];
            actv = (lane < D_INP) ? xp[lane]
                                  : hs[(lane - D_INP) < N_HID - 1 ? (lane - D_INP) : N_HID - 1];
            #pragma unroll
            for (int i = 0; i < 31; ++i) {
                const float a = RL(actv, i);
                accA += wA[i] * a;                    // L1 own
                if (i >= 11 && i < 21) accB += wB[i - 11] * a;   // L2 h1[0:10) partial
            }
        } else if (wid == 1) {
            // slice: lane i = h1[10+i], i<41
            actv = hs[10 + (lane < 41 ? lane : 40)];
            #pragma unroll
            for (int j = 0; j < 10; ++j) accB += wB[j] * RL(actv, j);        // L2 h1[10:20)
            #pragma unroll
            for (int i = 0; i < 31; ++i) accA += wA[i] * RL(actv, 10 + i);   // L1 h1[20:51)
        } else if (wid == 2) {
            // slice: lanes 0-30 = h1[20:51), lanes 31-40 = h2[0:10)
            actv = (lane < 31) ? hs[20 + lane]
                               : hs[56 + ((lane - 31) < 10 ? (lane - 31) : 9)];
            #pragma unroll
            for (int i = 0; i < 31; ++i) accA += wA[i] * RL(actv, i);
            #pragma unroll
            for (int j = 0; j < 10; ++j) accA += wB[j] * RL(actv, 31 + j);
        } else {
            // slice: lane i = h2[10+i], i<41
            actv = hs[56 + 10 + (lane < 41 ? lane : 40)];
            #pragma unroll
            for (int i = 0; i < 31; ++i) accA += wA[i] * RL(actv, i);
            #pragma unroll
            for (int j = 0; j < 10; ++j) accA += wB[j] * RL(actv, 31 + j);
        }

        if (valid) {                                  // publish partials
            if (wid == 0)      pl2[0][lane] = accB;
            else if (wid == 1) { pl1[lane] = accA; pl2[1][lane] = accB; }
            else if (wid == 3) pl2[2][lane] = accA;
        }
        __syncthreads();                              // B1

        if (wid == 0) {                               // c1/h1 update, step t
            const v4f g = accA + pl1[lane] + biasv;
            const float si = sigmoid_fast(g.x), sf = sigmoid_fast(g.y);
            const float tg = tanh_fast(g.z),    so = sigmoid_fast(g.w);
            cstate = sf * cstate + si * tg;
            const float hv = so * tanh_fast(cstate);
            if (valid) hstate[(t + 1) & 1][lane] = hv;
        } else if (wid == 2) {                        // c2/h2 update, step t-1
            if (t >= 1) {
                const v4f g = accA + pl2[0][lane] + pl2[1][lane] + pl2[2][lane] + biasv;
                const float si = sigmoid_fast(g.x), sf = sigmoid_fast(g.y);
                const float tg = tanh_fast(g.z),    so = sigmoid_fast(g.w);
                cstate = sf * cstate + si * tg;
                const float hv = so * tanh_fast(cstate);
                if (valid) hstate[(t + 1) & 1][56 + lane] = hv;
                float part = valid ? wlin * hv : 0.f; // fused projection
                #pragma unroll
                for (int off = 32; off > 0; off >>= 1)
                    part += __shfl_down(part, off, 64);
                if (lane == 0) outbuf[(t - 1) & 127] = part + blin;
            }
        } else if (wid == 1) {                        // coalesced out flush
            if ((t & 63) == 1 && t >= 65) {
                const int tb = (t - 65) + lane;
                out[(size_t)col * T_STEPS + tb] = outbuf[tb & 127];
            }
        }

        if ((t & 63) == 32) {                         // stash next x chunk
            const int buf = ((t >> 6) + 1) & 1;
            xput(buf, tid, xr0);
            xput(buf, tid + 256, xr1);
            if (tid < 192) xput(buf, tid + 512, xr2);
        }
        __syncthreads();                              // B2
    }

    if (wid == 1) {                                   // final 64 outputs
        const int idx = 4032 + lane;
        out[(size_t)col * T_STEPS + idx] = outbuf[idx & 127];
    }
}

extern "C" void kernel_launch(void* const* d_in, const int* in_sizes, int n_in,
                              void* d_out, int out_size, void* d_ws, size_t ws_size,
                              hipStream_t stream) {
    const float* input = (const float*)d_in[0];
    const float* W_ih1 = (const float*)d_in[1];
    const float* W_hh1 = (const float*)d_in[2];
    const float* b_ih1 = (const float*)d_in[3];
    const float* b_hh1 = (const float*)d_in[4];
    const float* W_ih2 = (const float*)d_in[5];
    const float* W_hh2 = (const float*)d_in[6];
    const float* b_ih2 = (const float*)d_in[7];
    const float* b_hh2 = (const float*)d_in[8];
    const float* W_lin = (const float*)d_in[9];
    const float* b_lin = (const float*)d_in[10];
    float* out = (float*)d_out;

    lstm2_sgprbc<<<M_BATCH, 256, 0, stream>>>(
        input, W_ih1, W_hh1, b_ih1, b_hh1,
        W_ih2, W_hh2, b_ih2, b_hh2, W_lin, b_lin, out);
}

// Round 5
// 5153.288 us; speedup vs baseline: 1.5473x; 1.0237x over previous
//
#include <hip/hip_runtime.h>

#define T_STEPS 4096
#define M_BATCH 512
#define D_INP   11
#define N_HID   51

typedef float v4f __attribute__((ext_vector_type(4)));

__device__ __forceinline__ float sigmoid_fast(float v) {
    return __builtin_amdgcn_rcpf(1.0f + __expf(-v));
}
__device__ __forceinline__ float tanh_fast(float v) {
    return 2.0f * __builtin_amdgcn_rcpf(1.0f + __expf(-2.0f * v)) - 1.0f;
}
// wave-uniform broadcast of lane l's value (compile-time l): v_readlane -> SGPR
__device__ __forceinline__ float RL(float v, int l) {
    return __uint_as_float(__builtin_amdgcn_readlane(__float_as_uint(v), l));
}

// Replicated-state k-split 2-layer LSTM.  One block (4 waves) per batch
// column, grid=512, 2 blocks/CU, 2 waves/SIMD (proven-safe round-3 skeleton:
// TWO barriers per step, single-buffered partial arrays).
// Each wave keeps h1/h2/c1/c2 REPLICATED in registers (lane n = unit n), so
// the gate phase readlane-broadcasts from its OWN registers - the h-state
// LDS round-trip and the owner-phase serialization of round 3 are gone.
// k-split (41 k-cols x 4 gates = 164 weight floats/wave, the proven-fitting
// budget at 2 waves/EU):
//   w0: L1 k={x(11), h1[0:30)}            -> pl1[0]
//   w1: L1 k=h1[30:51) + L2ih k=h1[0:20)  -> pl1[1], pl2[0]
//   w2: L2ih k=h1[20:51) + L2hh k=h2[0:10) -> pl2[1]
//   w3: L2hh k=h2[10:51)                  -> pl2[2]
// After B1: waves{0,1,2} redundantly update c1/h1, waves{2,3} update c2/h2
// (identical inputs -> identical results -> deterministic).  w3 owns the
// fused projection, w1 owns the coalesced output flush.  L2 lags L1 by one
// step.  w0 preloads next-step x before B2 to hide that LDS latency.
__attribute__((amdgpu_waves_per_eu(2, 2)))
__global__ __launch_bounds__(256)
void lstm2_replk(const float* __restrict__ input,
                 const float* __restrict__ W_ih1, const float* __restrict__ W_hh1,
                 const float* __restrict__ b_ih1, const float* __restrict__ b_hh1,
                 const float* __restrict__ W_ih2, const float* __restrict__ W_hh2,
                 const float* __restrict__ b_ih2, const float* __restrict__ b_hh2,
                 const float* __restrict__ W_lin, const float* __restrict__ b_lin,
                 float* __restrict__ out)
{
    const int  tid   = threadIdx.x;
    const int  col   = blockIdx.x;
    const int  wid   = tid >> 6;
    const int  lane  = tid & 63;
    const bool valid = lane < N_HID;
    const int  ln    = valid ? lane : N_HID - 1;   // clamped unit index

    __shared__ __align__(16) v4f   pl1[2][64];     // L1 partials [src][lane]
    __shared__ __align__(16) v4f   pl2[3][64];     // L2 partials [src][lane]
    __shared__ __align__(16) float xs[2][64 * 12]; // x chunks, stride 12
    __shared__ float outbuf[128];

    // ---- per-thread weights: wv[c] = v4f over gates (i,f,g,o), k-col c ----
    v4f wv[41];
    v4f b1v = {0.f,0.f,0.f,0.f}, b2v = {0.f,0.f,0.f,0.f};
    float wlin = 0.f;
    const float blin = b_lin[0];
    float c1 = 0.f, h1r = 0.f, c2 = 0.f, h2r = 0.f;

    #pragma unroll
    for (int q = 0; q < 4; ++q) {
        const int r = q * N_HID + ln;
        if (wid <= 2) b1v[q] = b_ih1[r] + b_hh1[r];
        if (wid >= 2) b2v[q] = b_ih2[r] + b_hh2[r];
        if (wid == 0) {
            #pragma unroll
            for (int i = 0; i < 11; ++i) wv[i][q]      = W_ih1[r * D_INP + i];
            #pragma unroll
            for (int i = 0; i < 30; ++i) wv[11 + i][q] = W_hh1[r * N_HID + i];
        } else if (wid == 1) {
            #pragma unroll
            for (int i = 0; i < 21; ++i) wv[i][q]      = W_hh1[r * N_HID + 30 + i];
            #pragma unroll
            for (int j = 0; j < 20; ++j) wv[21 + j][q] = W_ih2[r * N_HID + j];
        } else if (wid == 2) {
            #pragma unroll
            for (int i = 0; i < 31; ++i) wv[i][q]      = W_ih2[r * N_HID + 20 + i];
            #pragma unroll
            for (int j = 0; j < 10; ++j) wv[31 + j][q] = W_hh2[r * N_HID + j];
        } else {
            #pragma unroll
            for (int i = 0; i < 41; ++i) wv[i][q]      = W_hh2[r * N_HID + 10 + i];
        }
    }
    if (wid == 3) wlin = valid ? W_lin[lane] : 0.f;

    auto xload = [&](int c, int e) -> float {        // e in [0,704)
        int s = e / 11, d = e - s * 11;
        int tc = c * 64 + s; if (tc > T_STEPS - 1) tc = T_STEPS - 1;
        return input[((size_t)tc * M_BATCH + col) * D_INP + d];
    };
    auto xput = [&](int buf, int e, float v) {
        int s = e / 11, d = e - s * 11;
        xs[buf][s * 12 + d] = v;
    };

    // ---- zero-init xs (pads stay 0), stage chunk 0 ----
    for (int i = tid; i < 2 * 768; i += 256) (&xs[0][0])[i] = 0.f;
    __syncthreads();
    {
        xput(0, tid, xload(0, tid));
        xput(0, tid + 256, xload(0, tid + 256));
        if (tid < 192) xput(0, tid + 512, xload(0, tid + 512));
    }
    __syncthreads();

    const int xln = (lane < D_INP) ? lane : (D_INP - 1);
    float xv = (wid == 0) ? xs[0][xln] : 0.f;        // x for t=0 (lane d = x[d])
    float xr0 = 0.f, xr1 = 0.f, xr2 = 0.f;

    #pragma unroll 1
    for (int t = 0; t <= T_STEPS; ++t) {
        if ((t & 63) == 0) {                         // prefetch next x chunk
            const int c = (t >> 6) + 1;
            xr0 = xload(c, tid);
            xr1 = xload(c, tid + 256);
            if (tid < 192) xr2 = xload(c, tid + 512);
        }

        // ================= gate phase: own-register broadcasts =================
        v4f aP = {0.f,0.f,0.f,0.f}, aS = {0.f,0.f,0.f,0.f};
        if (wid == 0) {
            #pragma unroll
            for (int k = 0; k < 11; ++k) aP += wv[k] * RL(xv, k);
            #pragma unroll
            for (int i = 0; i < 30; ++i) aP += wv[11 + i] * RL(h1r, i);
        } else if (wid == 1) {
            #pragma unroll
            for (int i = 0; i < 21; ++i) aP += wv[i] * RL(h1r, 30 + i);
            #pragma unroll
            for (int j = 0; j < 20; ++j) aS += wv[21 + j] * RL(h1r, j);
        } else if (wid == 2) {
            #pragma unroll
            for (int i = 0; i < 31; ++i) aP += wv[i] * RL(h1r, 20 + i);
            #pragma unroll
            for (int j = 0; j < 10; ++j) aP += wv[31 + j] * RL(h2r, j);
        } else {
            #pragma unroll
            for (int i = 0; i < 41; ++i) aP += wv[i] * RL(h2r, 10 + i);
        }

        if (wid == 0)      pl1[0][lane] = aP;        // publish partials
        else if (wid == 1) { pl1[1][lane] = aP; pl2[0][lane] = aS; }
        else if (wid == 2) pl2[1][lane] = aP;
        else               pl2[2][lane] = aP;
        __syncthreads();                             // B1

        // ============ replicated state updates (no owner phase) ============
        if (wid <= 2) {                              // c1/h1, step t
            const v4f g1 = pl1[0][lane] + pl1[1][lane] + b1v;
            const float i1 = sigmoid_fast(g1.x), f1 = sigmoid_fast(g1.y);
            const float gg = tanh_fast(g1.z),    o1 = sigmoid_fast(g1.w);
            c1  = f1 * c1 + i1 * gg;
            h1r = o1 * tanh_fast(c1);
        }
        if (wid >= 2 && t >= 1) {                    // c2/h2, step t-1
            const v4f g2 = pl2[0][lane] + pl2[1][lane] + pl2[2][lane] + b2v;
            const float i2 = sigmoid_fast(g2.x), f2 = sigmoid_fast(g2.y);
            const float gg = tanh_fast(g2.z),    o2 = sigmoid_fast(g2.w);
            c2  = f2 * c2 + i2 * gg;
            h2r = o2 * tanh_fast(c2);
            if (wid == 3) {                          // fused projection
                float part = wlin * h2r;
                #pragma unroll
                for (int off = 32; off > 0; off >>= 1)
                    part += __shfl_down(part, off, 64);
                if (lane == 0) outbuf[(t - 1) & 127] = part + blin;
            }
        }
        if (wid == 1 && (t & 63) == 1 && t >= 65) {  // coalesced 64-wide flush
            const int tb = (t - 65) + lane;
            out[(size_t)col * T_STEPS + tb] = outbuf[tb & 127];
        }
        if ((t & 63) == 32) {                        // stash next x chunk
            const int buf = ((t >> 6) + 1) & 1;
            xput(buf, tid, xr0);
            xput(buf, tid + 256, xr1);
            if (tid < 192) xput(buf, tid + 512, xr2);
        }
        if (wid == 0) {                              // preload x for step t+1
            const int tn = t + 1;                    // (stash'd >=31 iters ago)
            xv = xs[(tn >> 6) & 1][(tn & 63) * 12 + xln];
        }
        __syncthreads();                             // B2
    }

    if (wid == 1) {                                  // final 64 outputs
        const int idx = 4032 + lane;
        out[(size_t)col * T_STEPS + idx] = outbuf[idx & 127];
    }
}

extern "C" void kernel_launch(void* const* d_in, const int* in_sizes, int n_in,
                              void* d_out, int out_size, void* d_ws, size_t ws_size,
                              hipStream_t stream) {
    const float* input = (const float*)d_in[0];
    const float* W_ih1 = (const float*)d_in[1];
    const float* W_hh1 = (const float*)d_in[2];
    const float* b_ih1 = (const float*)d_in[3];
    const float* b_hh1 = (const float*)d_in[4];
    const float* W_ih2 = (const float*)d_in[5];
    const float* W_hh2 = (const float*)d_in[6];
    const float* b_ih2 = (const float*)d_in[7];
    const float* b_hh2 = (const float*)d_in[8];
    const float* W_lin = (const float*)d_in[9];
    const float* b_lin = (const float*)d_in[10];
    float* out = (float*)d_out;

    lstm2_replk<<<M_BATCH, 256, 0, stream>>>(
        input, W_ih1, W_hh1, b_ih1, b_hh1,
        W_ih2, W_hh2, b_ih2, b_hh2, W_lin, b_lin, out);
}